// Round 7
// baseline (544.246 us; speedup 1.0000x reference)
//
#include <hip/hip_runtime.h>
#include <hip/hip_bf16.h>
#include <hip/hip_fp16.h>
#include <cstdint>
#include <cstddef>

// ---------------------------------------------------------------------------
// FeatureExtractorGAT, round 6 (resubmitted; R6 bench was an infra failure —
// UnresponsiveContainer — so these changes were never measured).
// Key change vs R5 (474 us; gat1 stuck ~155 us, bound by ~850 MB/pass of
// xh1h gather traffic through L2/L3):
//   ALGEBRAIC RESTRUCTURE of layer 1: aggregation commutes with x@W1, and
//   attention logits only need folded vectors. So aggregate in INPUT space:
//     agg[n,h,0:4] = sum_e p_e * x[src,0:4]   (gather 48 B/edge, tables
//     x 0.8 MB + a_s1 1.6 MB -> L2-resident)
//   then h[n] = ELU((agg[n,h]/s[n,h]) @ W1_head + b1)  (exact f32).
//   xh1h table (48 MB) + its 850 MB gather + xh1_kernel: eliminated.
//   src-sorted CSR fill (no FETCH win, +35 us): dropped.
// Layer 2 unchanged: gather fp16 xh2h (96 wide < 480 wide input space).
// ---------------------------------------------------------------------------

__global__ void prep_kernel(const float* __restrict__ W1,
                            const float* __restrict__ as1, const float* __restrict__ ad1,
                            const float* __restrict__ W2,
                            const float* __restrict__ as2, const float* __restrict__ ad2,
                            float* __restrict__ wa1, float* __restrict__ wa2)
{
    int t = threadIdx.x;
    if (t < 480) {
        float accs = 0.f, accd = 0.f;
        #pragma unroll 4
        for (int c = 0; c < 96; ++c) {
            float w = W2[t * 96 + c];
            accs += w * as2[c];
            accd += w * ad2[c];
        }
        wa2[t]       = accs;
        wa2[480 + t] = accd;
    }
    if (t < 32) {
        int k = t >> 3, h = t & 7;
        float accs = 0.f, accd = 0.f;
        for (int c = 0; c < 60; ++c) {
            float w = W1[k * 480 + h * 60 + c];
            accs += w * as1[h * 60 + c];
            accd += w * ad1[h * 60 + c];
        }
        wa1[k * 8 + h]      = accs;
        wa1[32 + k * 8 + h] = accd;
    }
}

__global__ void a1_kernel(const float* __restrict__ x, const float* __restrict__ wa1,
                          float* __restrict__ a_s1, float* __restrict__ a_d1, int N)
{
    int n = blockIdx.x * blockDim.x + threadIdx.x;
    if (n >= N) return;
    float4 xv = *(const float4*)(x + (size_t)n * 4);
    #pragma unroll
    for (int h = 0; h < 8; ++h) {
        float as = xv.x * wa1[h] + xv.y * wa1[8 + h] + xv.z * wa1[16 + h] + xv.w * wa1[24 + h];
        float ad = xv.x * wa1[32 + h] + xv.y * wa1[40 + h] + xv.z * wa1[48 + h] + xv.w * wa1[56 + h];
        a_s1[n * 8 + h] = as;
        a_d1[n * 8 + h] = ad;
    }
}

__global__ void degree_kernel(const int* __restrict__ ei, int E, int N, int* __restrict__ deg)
{
    int e = blockIdx.x * blockDim.x + threadIdx.x;
    if (e >= E + N) return;
    int d = (e < E) ? ei[E + e] : (e - E);
    atomicAdd(&deg[d], 1);
}

__global__ __launch_bounds__(1024) void scan_blk_kernel(const int* __restrict__ deg, int N,
                                                        int* __restrict__ offs,
                                                        int* __restrict__ partials)
{
    __shared__ int wsum[16];
    int i = blockIdx.x * 1024 + threadIdx.x;
    int lane = threadIdx.x & 63, wid = threadIdx.x >> 6;
    int v = (i < N) ? deg[i] : 0;
    int x = v;
    #pragma unroll
    for (int off = 1; off < 64; off <<= 1) {
        int y = __shfl_up(x, off, 64);
        if (lane >= off) x += y;
    }
    if (lane == 63) wsum[wid] = x;
    __syncthreads();
    if (wid == 0) {
        int wv = (lane < 16) ? wsum[lane] : 0;
        #pragma unroll
        for (int off = 1; off < 16; off <<= 1) {
            int y = __shfl_up(wv, off, 64);
            if (lane >= off) wv += y;
        }
        if (lane < 16) wsum[lane] = wv;
    }
    __syncthreads();
    int excl = (wid ? wsum[wid - 1] : 0) + x - v;
    if (i < N) offs[i] = excl;
    if (threadIdx.x == 1023) partials[blockIdx.x] = wsum[15];
}

__global__ void scan_part_kernel(int* __restrict__ partials, int nb,
                                 int* __restrict__ offs, int N)
{
    int lane = threadIdx.x & 63;
    int v = (lane < nb) ? partials[lane] : 0;
    int x = v;
    #pragma unroll
    for (int off = 1; off < 64; off <<= 1) {
        int y = __shfl_up(x, off, 64);
        if (lane >= off) x += y;
    }
    if (lane < nb) partials[lane] = x - v;
    if (lane == 63) offs[N] = x;
}

__global__ __launch_bounds__(1024) void scan_add_kernel(int* __restrict__ offs,
                                                        const int* __restrict__ partials,
                                                        int* __restrict__ cursor, int N)
{
    int i = blockIdx.x * 1024 + threadIdx.x;
    if (i < N) {
        int r = offs[i] + partials[blockIdx.x];
        offs[i]   = r;
        cursor[i] = r;
    }
}

__global__ void scatter_kernel(const int* __restrict__ ei, int E, int N,
                               int* __restrict__ cursor, int* __restrict__ csr)
{
    int e = blockIdx.x * blockDim.x + threadIdx.x;
    if (e >= E + N) return;
    int s, d;
    if (e < E) { s = ei[e]; d = ei[E + e]; } else { s = d = e - E; }
    int pos = atomicAdd(&cursor[d], 1);
    csr[pos] = s;
}

// ---- GAT layer 1 aggregation in INPUT space.
// Wave per node. Lanes 0-31 handle even edges, 32-63 odd edges; sub-lane
// sl = (h = sl>>2, c = sl&3). Per edge: p = exp(leaky(a_s1[src,h]+a_d1[n,h]));
// agg[h,c] += p * x[src,c]; s[h] += p. Tables x (0.8 MB) + a_s1 (1.6 MB)
// are L2-resident -> gathers are cheap.
__global__ __launch_bounds__(256) void gat1_agg(
    const int* __restrict__ row_ptr, const int* __restrict__ csr,
    const float* __restrict__ x,
    const float* __restrict__ a_s1, const float* __restrict__ a_d1,
    float* __restrict__ agg, float* __restrict__ ssum, int N)
{
    int gid = blockIdx.x * blockDim.x + threadIdx.x;
    int node = gid >> 6;
    if (node >= N) return;
    int lane = threadIdx.x & 63;
    int half = lane >> 5;      // 0: even edges, 1: odd edges
    int sl   = lane & 31;
    int h = sl >> 2, c = sl & 3;
    float adh = a_d1[(size_t)node * 8 + h];

    float aggv = 0.f, sv = 0.f;
    int beg = row_ptr[node], end = row_ptr[node + 1];
    constexpr int U = 4;                       // edges per half per iter
    for (int base = beg; base < end; base += 2 * U) {
        int   idx[U];
        float msk[U];
        #pragma unroll
        for (int u = 0; u < U; ++u) {
            int t = base + 2 * u + half;
            msk[u] = (t < end) ? 1.f : 0.f;
            idx[u] = csr[t < end ? t : (end - 1)];
        }
        float xv[U], av[U];
        #pragma unroll
        for (int u = 0; u < U; ++u) xv[u] = x[(size_t)idx[u] * 4 + c];
        #pragma unroll
        for (int u = 0; u < U; ++u) av[u] = a_s1[(size_t)idx[u] * 8 + h];
        #pragma unroll
        for (int u = 0; u < U; ++u) {
            float ev = av[u] + adh;
            ev = ev > 0.f ? ev : 0.2f * ev;
            float p = __expf(ev) * msk[u];
            sv   += p;
            aggv += p * xv[u];
        }
    }
    aggv += __shfl_xor(aggv, 32);
    sv   += __shfl_xor(sv, 32);
    if (lane < 32) {
        agg[(size_t)node * 32 + lane] = aggv;
        if (c == 0) ssum[(size_t)node * 8 + h] = sv;
    }
}

// ---- form h[n] = ELU((agg/s) @ W1_head + b1); fused layer-2 attention dots.
// Wave per node; lane l<60 owns cols [8l, 8l+8).
__global__ __launch_bounds__(256) void h_kernel(
    const float* __restrict__ agg, const float* __restrict__ ssum,
    const float* __restrict__ W1, const float* __restrict__ b1,
    const float* __restrict__ wa2,
    float* __restrict__ hbuf, float* __restrict__ a2s, float* __restrict__ a2d, int N)
{
    int gid = blockIdx.x * blockDim.x + threadIdx.x;
    int node = gid >> 6;
    if (node >= N) return;
    int lane = threadIdx.x & 63;
    bool act = lane < 60;
    int col0 = act ? lane * 8 : 0;
    int hA = col0 / 60;
    int hB = (col0 + 7) / 60;
    int sb = 60 * (hA + 1) - col0;  if (sb > 8) sb = 8;   // j<sb -> head hA

    float4 agA = *(const float4*)(agg + (size_t)node * 32 + hA * 4);
    float4 agB = *(const float4*)(agg + (size_t)node * 32 + hB * 4);
    float invA = 1.f / (ssum[(size_t)node * 8 + hA] + 1e-16f);
    float invB = 1.f / (ssum[(size_t)node * 8 + hB] + 1e-16f);

    float psrc = 0.f, pdst = 0.f;
    if (act) {
        float o[8];
        #pragma unroll
        for (int j = 0; j < 8; ++j) {
            int col = col0 + j;
            float4 ag = (j < sb) ? agA : agB;
            float inv = (j < sb) ? invA : invB;
            float raw = ag.x * W1[col] + ag.y * W1[480 + col]
                      + ag.z * W1[960 + col] + ag.w * W1[1440 + col];
            float v = raw * inv + b1[col];
            o[j] = v > 0.f ? v : expm1f(v);
            psrc += o[j] * wa2[col];
            pdst += o[j] * wa2[480 + col];
        }
        float4* hp = (float4*)(hbuf + (size_t)node * 480 + col0);
        hp[0] = make_float4(o[0], o[1], o[2], o[3]);
        hp[1] = make_float4(o[4], o[5], o[6], o[7]);
    }
    #pragma unroll
    for (int off = 32; off; off >>= 1) {
        psrc += __shfl_xor(psrc, off);
        pdst += __shfl_xor(pdst, off);
    }
    if (lane == 0) { a2s[node] = psrc; a2d[node] = pdst; }
}

// xh2h[N,96] = h[N,480] @ W2[480,96], fp16 out (conflict-free row map)
__global__ __launch_bounds__(256) void gemm2_kernel(
    const float* __restrict__ h, const float* __restrict__ W2,
    __half* __restrict__ xh2h, int N)
{
    __shared__ float hs[128][36];
    __shared__ float ws[32][96];
    int t = threadIdx.x;
    int nbase = blockIdx.x * 128;
    int tx = t & 15, ty = t >> 4;
    float acc[8][6];
    #pragma unroll
    for (int i = 0; i < 8; ++i)
        #pragma unroll
        for (int j = 0; j < 6; ++j) acc[i][j] = 0.f;

    for (int k0 = 0; k0 < 480; k0 += 32) {
        #pragma unroll
        for (int i = 0; i < 3; ++i) {
            int f = i * 256 + t;
            int kk = f / 24, c4 = f % 24;
            float4 v = *(const float4*)(W2 + (size_t)(k0 + kk) * 96 + c4 * 4);
            *(float4*)&ws[kk][c4 * 4] = v;
        }
        #pragma unroll
        for (int i = 0; i < 4; ++i) {
            int f = i * 256 + t;
            int node = f >> 3, k4 = f & 7;
            int gn = nbase + node; if (gn > N - 1) gn = N - 1;
            float4 v = *(const float4*)(h + (size_t)gn * 480 + k0 + k4 * 4);
            *(float4*)&hs[node][k4 * 4] = v;
        }
        __syncthreads();
        #pragma unroll
        for (int kk = 0; kk < 32; ++kk) {
            float hv[8], wv[6];
            #pragma unroll
            for (int i = 0; i < 8; ++i) hv[i] = hs[i * 16 + ty][kk];
            #pragma unroll
            for (int j = 0; j < 6; ++j) wv[j] = ws[kk][tx * 6 + j];
            #pragma unroll
            for (int i = 0; i < 8; ++i)
                #pragma unroll
                for (int j = 0; j < 6; ++j)
                    acc[i][j] += hv[i] * wv[j];
        }
        __syncthreads();
    }
    #pragma unroll
    for (int i = 0; i < 8; ++i) {
        int gn = nbase + i * 16 + ty;
        if (gn < N) {
            #pragma unroll
            for (int j = 0; j < 6; ++j)
                xh2h[(size_t)gn * 96 + tx * 6 + j] = __float2half(acc[i][j]);
        }
    }
}

// ---- GAT layer 2, fused: 1 wave per node, U=8; lane<48 owns cols {2l,2l+1}
__global__ __launch_bounds__(256) void gat2_fused(
    const int* __restrict__ row_ptr, const int* __restrict__ csr,
    const float* __restrict__ a_s2, const float* __restrict__ a_d2,
    const __half* __restrict__ xh2h, const float* __restrict__ b2,
    float* __restrict__ out, int N)
{
    int gid = blockIdx.x * blockDim.x + threadIdx.x;
    int node = gid >> 6;
    if (node >= N) return;
    int lane = threadIdx.x & 63;
    bool act = lane < 48;
    float adv = a_d2[node];
    float s = 0.f, ax = 0.f, ay = 0.f;
    int beg = row_ptr[node], end = row_ptr[node + 1];
    constexpr int U = 8;
    for (int e0 = beg; e0 < end; e0 += U) {
        int cnt = end - e0;  if (cnt > U) cnt = U;
        int srcs[U];
        #pragma unroll
        for (int u = 0; u < U; ++u) {
            int t = e0 + u;
            srcs[u] = csr[t < end ? t : (end - 1)];
        }
        float asv[U];
        #pragma unroll
        for (int u = 0; u < U; ++u) asv[u] = a_s2[srcs[u]];
        __half2 gv[U];
        if (act) {
            #pragma unroll
            for (int u = 0; u < U; ++u)
                gv[u] = ((const __half2*)(xh2h + (size_t)srcs[u] * 96))[lane];
        }
        #pragma unroll
        for (int u = 0; u < U; ++u) {
            float ev = asv[u] + adv;
            ev = ev > 0.f ? ev : 0.2f * ev;
            float p = __expf(ev) * ((u < cnt) ? 1.f : 0.f);
            s += p;
            if (act) {
                float2 fg = __half22float2(gv[u]);
                ax += p * fg.x;
                ay += p * fg.y;
            }
        }
    }
    float inv = 1.f / (s + 1e-16f);
    if (act) {
        out[(size_t)node * 96 + 2 * lane]     = ax * inv + b2[2 * lane];
        out[(size_t)node * 96 + 2 * lane + 1] = ay * inv + b2[2 * lane + 1];
    }
}

extern "C" void kernel_launch(void* const* d_in, const int* in_sizes, int n_in,
                              void* d_out, int out_size, void* d_ws, size_t ws_size,
                              hipStream_t stream)
{
    const float* x   = (const float*)d_in[0];
    const int*   ei  = (const int*)  d_in[1];
    const float* W1  = (const float*)d_in[2];
    const float* as1 = (const float*)d_in[3];
    const float* ad1 = (const float*)d_in[4];
    const float* b1  = (const float*)d_in[5];
    const float* W2  = (const float*)d_in[6];
    const float* as2 = (const float*)d_in[7];
    const float* ad2 = (const float*)d_in[8];
    const float* b2  = (const float*)d_in[9];
    float* out = (float*)d_out;

    int N  = in_sizes[0] / 4;   // 50000
    int E  = in_sizes[1] / 2;   // 800000
    int EP = E + N;
    int NB = (N + 1023) / 1024; // <= 64 scan blocks (49 here)

    float* f = (float*)d_ws;
    float* hbuf  = f;  f += (size_t)N * 480;
    float* a_s1  = f;  f += (size_t)N * 8;
    float* a_d1  = f;  f += (size_t)N * 8;
    float* agg   = f;  f += (size_t)N * 32;
    float* ssum  = f;  f += (size_t)N * 8;
    float* a_s2  = f;  f += N;
    float* a_d2  = f;  f += N;
    float* wa1   = f;  f += 64;
    float* wa2   = f;  f += 960;
    __half* xh2h = (__half*)f;
    __half* hp   = xh2h + (size_t)N * 96;
    int* ip      = (int*)hp;
    int* row_ptr = ip;  ip += N + 1;
    int* deg     = ip;  ip += N;
    int* cursor  = ip;  ip += N;
    int* partials= ip;  ip += 64;
    int* csr     = ip;  ip += EP;

    size_t needed = (size_t)((char*)ip - (char*)d_ws);
    if (needed > ws_size) return;  // loud failure if scratch too small

    hipMemsetAsync(deg, 0, (size_t)N * sizeof(int), stream);
    prep_kernel<<<1, 512, 0, stream>>>(W1, as1, ad1, W2, as2, ad2, wa1, wa2);
    a1_kernel<<<(N + 255) / 256, 256, 0, stream>>>(x, wa1, a_s1, a_d1, N);
    degree_kernel<<<(EP + 255) / 256, 256, 0, stream>>>(ei, E, N, deg);
    scan_blk_kernel<<<NB, 1024, 0, stream>>>(deg, N, row_ptr, partials);
    scan_part_kernel<<<1, 64, 0, stream>>>(partials, NB, row_ptr, N);
    scan_add_kernel<<<NB, 1024, 0, stream>>>(row_ptr, partials, cursor, N);
    scatter_kernel<<<(EP + 255) / 256, 256, 0, stream>>>(ei, E, N, cursor, csr);
    gat1_agg<<<(N * 64 + 255) / 256, 256, 0, stream>>>(
        row_ptr, csr, x, a_s1, a_d1, agg, ssum, N);
    h_kernel<<<(N * 64 + 255) / 256, 256, 0, stream>>>(
        agg, ssum, W1, b1, wa2, hbuf, a_s2, a_d2, N);
    gemm2_kernel<<<(N + 127) / 128, 256, 0, stream>>>(hbuf, W2, xh2h, N);
    gat2_fused<<<(N * 64 + 255) / 256, 256, 0, stream>>>(
        row_ptr, csr, a_s2, a_d2, xh2h, b2, out, N);
}

// Round 8
// 309.450 us; speedup vs baseline: 1.7588x; 1.7588x over previous
//
#include <hip/hip_runtime.h>
#include <hip/hip_bf16.h>
#include <hip/hip_fp16.h>
#include <cstdint>
#include <cstddef>

// ---------------------------------------------------------------------------
// FeatureExtractorGAT, round 8.
// Single change vs R7 (544 us; h_kernel = 298 us @ 13% VALU / 4% HBM / 87%
// occ -> TA/L1-throughput bound: lane-owns-8-contiguous-cols layout made
// every wave-wide load a stride-32B scatter touching ~30 lines, with each
// W1 line re-touched 8x):
//   h_kernel column mapping TRANSPOSED: lane l<60 handles col h*60+l,
//   h=0..7. All W1/wa2/b1/hbuf accesses are now wave-contiguous; agg/ssum
//   are wave-uniform broadcasts per h; head-split (hA/hB) logic gone.
//   prep_kernel additionally emits w1t[col] = float4(W1[k*480+col]) and
//   wa2t[col] = float2(wa2_src, wa2_dst) so per (lane,h) it's 1 float4 +
//   1 float2 + 1 float load. ~6.5x fewer L1 line-transactions per wave.
// Everything else byte-identical to R7.
// ---------------------------------------------------------------------------

__global__ void prep_kernel(const float* __restrict__ W1,
                            const float* __restrict__ as1, const float* __restrict__ ad1,
                            const float* __restrict__ W2,
                            const float* __restrict__ as2, const float* __restrict__ ad2,
                            float* __restrict__ wa1, float4* __restrict__ w1t,
                            float2* __restrict__ wa2t)
{
    int t = threadIdx.x;
    if (t < 480) {
        float accs = 0.f, accd = 0.f;
        #pragma unroll 4
        for (int c = 0; c < 96; ++c) {
            float w = W2[t * 96 + c];
            accs += w * as2[c];
            accd += w * ad2[c];
        }
        wa2t[t] = make_float2(accs, accd);
        w1t[t]  = make_float4(W1[t], W1[480 + t], W1[960 + t], W1[1440 + t]);
    }
    if (t < 32) {
        int k = t >> 3, h = t & 7;
        float accs = 0.f, accd = 0.f;
        for (int c = 0; c < 60; ++c) {
            float w = W1[k * 480 + h * 60 + c];
            accs += w * as1[h * 60 + c];
            accd += w * ad1[h * 60 + c];
        }
        wa1[k * 8 + h]      = accs;
        wa1[32 + k * 8 + h] = accd;
    }
}

__global__ void a1_kernel(const float* __restrict__ x, const float* __restrict__ wa1,
                          float* __restrict__ a_s1, float* __restrict__ a_d1, int N)
{
    int n = blockIdx.x * blockDim.x + threadIdx.x;
    if (n >= N) return;
    float4 xv = *(const float4*)(x + (size_t)n * 4);
    #pragma unroll
    for (int h = 0; h < 8; ++h) {
        float as = xv.x * wa1[h] + xv.y * wa1[8 + h] + xv.z * wa1[16 + h] + xv.w * wa1[24 + h];
        float ad = xv.x * wa1[32 + h] + xv.y * wa1[40 + h] + xv.z * wa1[48 + h] + xv.w * wa1[56 + h];
        a_s1[n * 8 + h] = as;
        a_d1[n * 8 + h] = ad;
    }
}

__global__ void degree_kernel(const int* __restrict__ ei, int E, int N, int* __restrict__ deg)
{
    int e = blockIdx.x * blockDim.x + threadIdx.x;
    if (e >= E + N) return;
    int d = (e < E) ? ei[E + e] : (e - E);
    atomicAdd(&deg[d], 1);
}

__global__ __launch_bounds__(1024) void scan_blk_kernel(const int* __restrict__ deg, int N,
                                                        int* __restrict__ offs,
                                                        int* __restrict__ partials)
{
    __shared__ int wsum[16];
    int i = blockIdx.x * 1024 + threadIdx.x;
    int lane = threadIdx.x & 63, wid = threadIdx.x >> 6;
    int v = (i < N) ? deg[i] : 0;
    int x = v;
    #pragma unroll
    for (int off = 1; off < 64; off <<= 1) {
        int y = __shfl_up(x, off, 64);
        if (lane >= off) x += y;
    }
    if (lane == 63) wsum[wid] = x;
    __syncthreads();
    if (wid == 0) {
        int wv = (lane < 16) ? wsum[lane] : 0;
        #pragma unroll
        for (int off = 1; off < 16; off <<= 1) {
            int y = __shfl_up(wv, off, 64);
            if (lane >= off) wv += y;
        }
        if (lane < 16) wsum[lane] = wv;
    }
    __syncthreads();
    int excl = (wid ? wsum[wid - 1] : 0) + x - v;
    if (i < N) offs[i] = excl;
    if (threadIdx.x == 1023) partials[blockIdx.x] = wsum[15];
}

__global__ void scan_part_kernel(int* __restrict__ partials, int nb,
                                 int* __restrict__ offs, int N)
{
    int lane = threadIdx.x & 63;
    int v = (lane < nb) ? partials[lane] : 0;
    int x = v;
    #pragma unroll
    for (int off = 1; off < 64; off <<= 1) {
        int y = __shfl_up(x, off, 64);
        if (lane >= off) x += y;
    }
    if (lane < nb) partials[lane] = x - v;
    if (lane == 63) offs[N] = x;
}

__global__ __launch_bounds__(1024) void scan_add_kernel(int* __restrict__ offs,
                                                        const int* __restrict__ partials,
                                                        int* __restrict__ cursor, int N)
{
    int i = blockIdx.x * 1024 + threadIdx.x;
    if (i < N) {
        int r = offs[i] + partials[blockIdx.x];
        offs[i]   = r;
        cursor[i] = r;
    }
}

__global__ void scatter_kernel(const int* __restrict__ ei, int E, int N,
                               int* __restrict__ cursor, int* __restrict__ csr)
{
    int e = blockIdx.x * blockDim.x + threadIdx.x;
    if (e >= E + N) return;
    int s, d;
    if (e < E) { s = ei[e]; d = ei[E + e]; } else { s = d = e - E; }
    int pos = atomicAdd(&cursor[d], 1);
    csr[pos] = s;
}

// ---- GAT layer 1 aggregation in INPUT space (unchanged from R7).
__global__ __launch_bounds__(256) void gat1_agg(
    const int* __restrict__ row_ptr, const int* __restrict__ csr,
    const float* __restrict__ x,
    const float* __restrict__ a_s1, const float* __restrict__ a_d1,
    float* __restrict__ agg, float* __restrict__ ssum, int N)
{
    int gid = blockIdx.x * blockDim.x + threadIdx.x;
    int node = gid >> 6;
    if (node >= N) return;
    int lane = threadIdx.x & 63;
    int half = lane >> 5;      // 0: even edges, 1: odd edges
    int sl   = lane & 31;
    int h = sl >> 2, c = sl & 3;
    float adh = a_d1[(size_t)node * 8 + h];

    float aggv = 0.f, sv = 0.f;
    int beg = row_ptr[node], end = row_ptr[node + 1];
    constexpr int U = 4;
    for (int base = beg; base < end; base += 2 * U) {
        int   idx[U];
        float msk[U];
        #pragma unroll
        for (int u = 0; u < U; ++u) {
            int t = base + 2 * u + half;
            msk[u] = (t < end) ? 1.f : 0.f;
            idx[u] = csr[t < end ? t : (end - 1)];
        }
        float xv[U], av[U];
        #pragma unroll
        for (int u = 0; u < U; ++u) xv[u] = x[(size_t)idx[u] * 4 + c];
        #pragma unroll
        for (int u = 0; u < U; ++u) av[u] = a_s1[(size_t)idx[u] * 8 + h];
        #pragma unroll
        for (int u = 0; u < U; ++u) {
            float ev = av[u] + adh;
            ev = ev > 0.f ? ev : 0.2f * ev;
            float p = __expf(ev) * msk[u];
            sv   += p;
            aggv += p * xv[u];
        }
    }
    aggv += __shfl_xor(aggv, 32);
    sv   += __shfl_xor(sv, 32);
    if (lane < 32) {
        agg[(size_t)node * 32 + lane] = aggv;
        if (c == 0) ssum[(size_t)node * 8 + h] = sv;
    }
}

// ---- h[n] = ELU((agg/s) @ W1_head + b1) + fused layer-2 attention dots.
// NEW mapping: lane l<60 handles col = h*60 + l for h = 0..7.
// All W1T/wa2t/b1/hbuf accesses are wave-contiguous; agg/ssum uniform per h.
__global__ __launch_bounds__(256) void h_kernel(
    const float* __restrict__ agg, const float* __restrict__ ssum,
    const float4* __restrict__ w1t, const float* __restrict__ b1,
    const float2* __restrict__ wa2t,
    float* __restrict__ hbuf, float* __restrict__ a2s, float* __restrict__ a2d, int N)
{
    int gid = blockIdx.x * blockDim.x + threadIdx.x;
    int node = gid >> 6;
    if (node >= N) return;
    int lane = threadIdx.x & 63;
    bool act = lane < 60;

    float psrc = 0.f, pdst = 0.f;
    #pragma unroll
    for (int h = 0; h < 8; ++h) {
        float4 ag  = *(const float4*)(agg + (size_t)node * 32 + h * 4);  // uniform
        float  inv = 1.f / (ssum[(size_t)node * 8 + h] + 1e-16f);        // uniform
        if (act) {
            int col = h * 60 + lane;
            float4 w  = w1t[col];
            float raw = ag.x * w.x + ag.y * w.y + ag.z * w.z + ag.w * w.w;
            float v   = raw * inv + b1[col];
            float o   = v > 0.f ? v : expm1f(v);
            hbuf[(size_t)node * 480 + col] = o;
            float2 wz = wa2t[col];
            psrc += o * wz.x;
            pdst += o * wz.y;
        }
    }
    #pragma unroll
    for (int off = 32; off; off >>= 1) {
        psrc += __shfl_xor(psrc, off);
        pdst += __shfl_xor(pdst, off);
    }
    if (lane == 0) { a2s[node] = psrc; a2d[node] = pdst; }
}

// xh2h[N,96] = h[N,480] @ W2[480,96], fp16 out (conflict-free row map)
__global__ __launch_bounds__(256) void gemm2_kernel(
    const float* __restrict__ h, const float* __restrict__ W2,
    __half* __restrict__ xh2h, int N)
{
    __shared__ float hs[128][36];
    __shared__ float ws[32][96];
    int t = threadIdx.x;
    int nbase = blockIdx.x * 128;
    int tx = t & 15, ty = t >> 4;
    float acc[8][6];
    #pragma unroll
    for (int i = 0; i < 8; ++i)
        #pragma unroll
        for (int j = 0; j < 6; ++j) acc[i][j] = 0.f;

    for (int k0 = 0; k0 < 480; k0 += 32) {
        #pragma unroll
        for (int i = 0; i < 3; ++i) {
            int f = i * 256 + t;
            int kk = f / 24, c4 = f % 24;
            float4 v = *(const float4*)(W2 + (size_t)(k0 + kk) * 96 + c4 * 4);
            *(float4*)&ws[kk][c4 * 4] = v;
        }
        #pragma unroll
        for (int i = 0; i < 4; ++i) {
            int f = i * 256 + t;
            int node = f >> 3, k4 = f & 7;
            int gn = nbase + node; if (gn > N - 1) gn = N - 1;
            float4 v = *(const float4*)(h + (size_t)gn * 480 + k0 + k4 * 4);
            *(float4*)&hs[node][k4 * 4] = v;
        }
        __syncthreads();
        #pragma unroll
        for (int kk = 0; kk < 32; ++kk) {
            float hv[8], wv[6];
            #pragma unroll
            for (int i = 0; i < 8; ++i) hv[i] = hs[i * 16 + ty][kk];
            #pragma unroll
            for (int j = 0; j < 6; ++j) wv[j] = ws[kk][tx * 6 + j];
            #pragma unroll
            for (int i = 0; i < 8; ++i)
                #pragma unroll
                for (int j = 0; j < 6; ++j)
                    acc[i][j] += hv[i] * wv[j];
        }
        __syncthreads();
    }
    #pragma unroll
    for (int i = 0; i < 8; ++i) {
        int gn = nbase + i * 16 + ty;
        if (gn < N) {
            #pragma unroll
            for (int j = 0; j < 6; ++j)
                xh2h[(size_t)gn * 96 + tx * 6 + j] = __float2half(acc[i][j]);
        }
    }
}

// ---- GAT layer 2, fused: 1 wave per node, U=8; lane<48 owns cols {2l,2l+1}
__global__ __launch_bounds__(256) void gat2_fused(
    const int* __restrict__ row_ptr, const int* __restrict__ csr,
    const float* __restrict__ a_s2, const float* __restrict__ a_d2,
    const __half* __restrict__ xh2h, const float* __restrict__ b2,
    float* __restrict__ out, int N)
{
    int gid = blockIdx.x * blockDim.x + threadIdx.x;
    int node = gid >> 6;
    if (node >= N) return;
    int lane = threadIdx.x & 63;
    bool act = lane < 48;
    float adv = a_d2[node];
    float s = 0.f, ax = 0.f, ay = 0.f;
    int beg = row_ptr[node], end = row_ptr[node + 1];
    constexpr int U = 8;
    for (int e0 = beg; e0 < end; e0 += U) {
        int cnt = end - e0;  if (cnt > U) cnt = U;
        int srcs[U];
        #pragma unroll
        for (int u = 0; u < U; ++u) {
            int t = e0 + u;
            srcs[u] = csr[t < end ? t : (end - 1)];
        }
        float asv[U];
        #pragma unroll
        for (int u = 0; u < U; ++u) asv[u] = a_s2[srcs[u]];
        __half2 gv[U];
        if (act) {
            #pragma unroll
            for (int u = 0; u < U; ++u)
                gv[u] = ((const __half2*)(xh2h + (size_t)srcs[u] * 96))[lane];
        }
        #pragma unroll
        for (int u = 0; u < U; ++u) {
            float ev = asv[u] + adv;
            ev = ev > 0.f ? ev : 0.2f * ev;
            float p = __expf(ev) * ((u < cnt) ? 1.f : 0.f);
            s += p;
            if (act) {
                float2 fg = __half22float2(gv[u]);
                ax += p * fg.x;
                ay += p * fg.y;
            }
        }
    }
    float inv = 1.f / (s + 1e-16f);
    if (act) {
        out[(size_t)node * 96 + 2 * lane]     = ax * inv + b2[2 * lane];
        out[(size_t)node * 96 + 2 * lane + 1] = ay * inv + b2[2 * lane + 1];
    }
}

extern "C" void kernel_launch(void* const* d_in, const int* in_sizes, int n_in,
                              void* d_out, int out_size, void* d_ws, size_t ws_size,
                              hipStream_t stream)
{
    const float* x   = (const float*)d_in[0];
    const int*   ei  = (const int*)  d_in[1];
    const float* W1  = (const float*)d_in[2];
    const float* as1 = (const float*)d_in[3];
    const float* ad1 = (const float*)d_in[4];
    const float* b1  = (const float*)d_in[5];
    const float* W2  = (const float*)d_in[6];
    const float* as2 = (const float*)d_in[7];
    const float* ad2 = (const float*)d_in[8];
    const float* b2  = (const float*)d_in[9];
    float* out = (float*)d_out;

    int N  = in_sizes[0] / 4;   // 50000
    int E  = in_sizes[1] / 2;   // 800000
    int EP = E + N;
    int NB = (N + 1023) / 1024; // <= 64 scan blocks (49 here)

    float* f = (float*)d_ws;
    float* hbuf  = f;  f += (size_t)N * 480;
    float* a_s1  = f;  f += (size_t)N * 8;
    float* a_d1  = f;  f += (size_t)N * 8;
    float* agg   = f;  f += (size_t)N * 32;
    float* ssum  = f;  f += (size_t)N * 8;
    float* a_s2  = f;  f += N;
    float* a_d2  = f;  f += N;
    float* wa1   = f;  f += 64;
    float4* w1t  = (float4*)f;  f += 480 * 4;   // 16B-aligned (all prior counts %4==0)
    float2* wa2t = (float2*)f;  f += 480 * 2;
    __half* xh2h = (__half*)f;
    __half* hp   = xh2h + (size_t)N * 96;
    int* ip      = (int*)hp;
    int* row_ptr = ip;  ip += N + 1;
    int* deg     = ip;  ip += N;
    int* cursor  = ip;  ip += N;
    int* partials= ip;  ip += 64;
    int* csr     = ip;  ip += EP;

    size_t needed = (size_t)((char*)ip - (char*)d_ws);
    if (needed > ws_size) return;  // loud failure if scratch too small

    hipMemsetAsync(deg, 0, (size_t)N * sizeof(int), stream);
    prep_kernel<<<1, 512, 0, stream>>>(W1, as1, ad1, W2, as2, ad2, wa1, w1t, wa2t);
    a1_kernel<<<(N + 255) / 256, 256, 0, stream>>>(x, wa1, a_s1, a_d1, N);
    degree_kernel<<<(EP + 255) / 256, 256, 0, stream>>>(ei, E, N, deg);
    scan_blk_kernel<<<NB, 1024, 0, stream>>>(deg, N, row_ptr, partials);
    scan_part_kernel<<<1, 64, 0, stream>>>(partials, NB, row_ptr, N);
    scan_add_kernel<<<NB, 1024, 0, stream>>>(row_ptr, partials, cursor, N);
    scatter_kernel<<<(EP + 255) / 256, 256, 0, stream>>>(ei, E, N, cursor, csr);
    gat1_agg<<<(N * 64 + 255) / 256, 256, 0, stream>>>(
        row_ptr, csr, x, a_s1, a_d1, agg, ssum, N);
    h_kernel<<<(N * 64 + 255) / 256, 256, 0, stream>>>(
        agg, ssum, w1t, b1, wa2t, hbuf, a_s2, a_d2, N);
    gemm2_kernel<<<(N + 127) / 128, 256, 0, stream>>>(hbuf, W2, xh2h, N);
    gat2_fused<<<(N * 64 + 255) / 256, 256, 0, stream>>>(
        row_ptr, csr, a_s2, a_d2, xh2h, b2, out, N);
}

// Round 11
// 266.997 us; speedup vs baseline: 2.0384x; 1.1590x over previous
//
#include <hip/hip_runtime.h>
#include <hip/hip_bf16.h>
#include <hip/hip_fp16.h>
#include <cstdint>
#include <cstddef>

// ---------------------------------------------------------------------------
// FeatureExtractorGAT, round 9 design (3rd submission; R9/R10 benches were
// infra failures — UnresponsiveContainer — so this has never been measured).
// Changes vs R8 (309 us; gemm2 = 80 us @ 42% VALU / 12% occ, f32 vector GEMM,
// launch-starved at 391 blocks; h_kernel fixed and out of top-5):
//  - gemm2 -> MFMA fp16: h stored fp16 (only gemm2 consumes it), W2
//    pre-transposed to [96][480] fp16, v_mfma_f32_16x16x32_f16 with f32
//    accum. Wave = 16 rows x 96 cols, K=480 -> 15 k-steps x 6 MFMA.
//    A-frag: row=lane&15, k=(lane>>4)*8+i (one 16B load); B-frag same
//    pattern from W2t; C/D: col=lane&15, row=(lane>>4)*4+reg (m89 layout).
//    Grid 782 blocks (64 rows/block, 4 waves).
//  - h_kernel writes fp16 (halves its write traffic).
// Everything else unchanged from R8.
// ---------------------------------------------------------------------------

typedef _Float16 half8 __attribute__((ext_vector_type(8)));
typedef float floatx4 __attribute__((ext_vector_type(4)));

__global__ void prep_kernel(const float* __restrict__ W1,
                            const float* __restrict__ as1, const float* __restrict__ ad1,
                            const float* __restrict__ W2,
                            const float* __restrict__ as2, const float* __restrict__ ad2,
                            float* __restrict__ wa1, float4* __restrict__ w1t,
                            float2* __restrict__ wa2t)
{
    int t = threadIdx.x;
    if (t < 480) {
        float accs = 0.f, accd = 0.f;
        #pragma unroll 4
        for (int c = 0; c < 96; ++c) {
            float w = W2[t * 96 + c];
            accs += w * as2[c];
            accd += w * ad2[c];
        }
        wa2t[t] = make_float2(accs, accd);
        w1t[t]  = make_float4(W1[t], W1[480 + t], W1[960 + t], W1[1440 + t]);
    }
    if (t < 32) {
        int k = t >> 3, h = t & 7;
        float accs = 0.f, accd = 0.f;
        for (int c = 0; c < 60; ++c) {
            float w = W1[k * 480 + h * 60 + c];
            accs += w * as1[h * 60 + c];
            accd += w * ad1[h * 60 + c];
        }
        wa1[k * 8 + h]      = accs;
        wa1[32 + k * 8 + h] = accd;
    }
}

// W2t[n][k] = W2[k][n], fp16
__global__ void w2t_kernel(const float* __restrict__ W2, __half* __restrict__ w2t)
{
    int idx = blockIdx.x * 256 + threadIdx.x;
    if (idx >= 96 * 480) return;
    int n = idx / 480, k = idx - n * 480;
    w2t[idx] = __float2half(W2[k * 96 + n]);
}

__global__ void a1_kernel(const float* __restrict__ x, const float* __restrict__ wa1,
                          float* __restrict__ a_s1, float* __restrict__ a_d1, int N)
{
    int n = blockIdx.x * blockDim.x + threadIdx.x;
    if (n >= N) return;
    float4 xv = *(const float4*)(x + (size_t)n * 4);
    #pragma unroll
    for (int h = 0; h < 8; ++h) {
        float as = xv.x * wa1[h] + xv.y * wa1[8 + h] + xv.z * wa1[16 + h] + xv.w * wa1[24 + h];
        float ad = xv.x * wa1[32 + h] + xv.y * wa1[40 + h] + xv.z * wa1[48 + h] + xv.w * wa1[56 + h];
        a_s1[n * 8 + h] = as;
        a_d1[n * 8 + h] = ad;
    }
}

__global__ void degree_kernel(const int* __restrict__ ei, int E, int N, int* __restrict__ deg)
{
    int e = blockIdx.x * blockDim.x + threadIdx.x;
    if (e >= E + N) return;
    int d = (e < E) ? ei[E + e] : (e - E);
    atomicAdd(&deg[d], 1);
}

__global__ __launch_bounds__(1024) void scan_blk_kernel(const int* __restrict__ deg, int N,
                                                        int* __restrict__ offs,
                                                        int* __restrict__ partials)
{
    __shared__ int wsum[16];
    int i = blockIdx.x * 1024 + threadIdx.x;
    int lane = threadIdx.x & 63, wid = threadIdx.x >> 6;
    int v = (i < N) ? deg[i] : 0;
    int x = v;
    #pragma unroll
    for (int off = 1; off < 64; off <<= 1) {
        int y = __shfl_up(x, off, 64);
        if (lane >= off) x += y;
    }
    if (lane == 63) wsum[wid] = x;
    __syncthreads();
    if (wid == 0) {
        int wv = (lane < 16) ? wsum[lane] : 0;
        #pragma unroll
        for (int off = 1; off < 16; off <<= 1) {
            int y = __shfl_up(wv, off, 64);
            if (lane >= off) wv += y;
        }
        if (lane < 16) wsum[lane] = wv;
    }
    __syncthreads();
    int excl = (wid ? wsum[wid - 1] : 0) + x - v;
    if (i < N) offs[i] = excl;
    if (threadIdx.x == 1023) partials[blockIdx.x] = wsum[15];
}

__global__ void scan_part_kernel(int* __restrict__ partials, int nb,
                                 int* __restrict__ offs, int N)
{
    int lane = threadIdx.x & 63;
    int v = (lane < nb) ? partials[lane] : 0;
    int x = v;
    #pragma unroll
    for (int off = 1; off < 64; off <<= 1) {
        int y = __shfl_up(x, off, 64);
        if (lane >= off) x += y;
    }
    if (lane < nb) partials[lane] = x - v;
    if (lane == 63) offs[N] = x;
}

__global__ __launch_bounds__(1024) void scan_add_kernel(int* __restrict__ offs,
                                                        const int* __restrict__ partials,
                                                        int* __restrict__ cursor, int N)
{
    int i = blockIdx.x * 1024 + threadIdx.x;
    if (i < N) {
        int r = offs[i] + partials[blockIdx.x];
        offs[i]   = r;
        cursor[i] = r;
    }
}

__global__ void scatter_kernel(const int* __restrict__ ei, int E, int N,
                               int* __restrict__ cursor, int* __restrict__ csr)
{
    int e = blockIdx.x * blockDim.x + threadIdx.x;
    if (e >= E + N) return;
    int s, d;
    if (e < E) { s = ei[e]; d = ei[E + e]; } else { s = d = e - E; }
    int pos = atomicAdd(&cursor[d], 1);
    csr[pos] = s;
}

// ---- GAT layer 1 aggregation in INPUT space (unchanged).
__global__ __launch_bounds__(256) void gat1_agg(
    const int* __restrict__ row_ptr, const int* __restrict__ csr,
    const float* __restrict__ x,
    const float* __restrict__ a_s1, const float* __restrict__ a_d1,
    float* __restrict__ agg, float* __restrict__ ssum, int N)
{
    int gid = blockIdx.x * blockDim.x + threadIdx.x;
    int node = gid >> 6;
    if (node >= N) return;
    int lane = threadIdx.x & 63;
    int half = lane >> 5;
    int sl   = lane & 31;
    int h = sl >> 2, c = sl & 3;
    float adh = a_d1[(size_t)node * 8 + h];

    float aggv = 0.f, sv = 0.f;
    int beg = row_ptr[node], end = row_ptr[node + 1];
    constexpr int U = 4;
    for (int base = beg; base < end; base += 2 * U) {
        int   idx[U];
        float msk[U];
        #pragma unroll
        for (int u = 0; u < U; ++u) {
            int t = base + 2 * u + half;
            msk[u] = (t < end) ? 1.f : 0.f;
            idx[u] = csr[t < end ? t : (end - 1)];
        }
        float xv[U], av[U];
        #pragma unroll
        for (int u = 0; u < U; ++u) xv[u] = x[(size_t)idx[u] * 4 + c];
        #pragma unroll
        for (int u = 0; u < U; ++u) av[u] = a_s1[(size_t)idx[u] * 8 + h];
        #pragma unroll
        for (int u = 0; u < U; ++u) {
            float ev = av[u] + adh;
            ev = ev > 0.f ? ev : 0.2f * ev;
            float p = __expf(ev) * msk[u];
            sv   += p;
            aggv += p * xv[u];
        }
    }
    aggv += __shfl_xor(aggv, 32);
    sv   += __shfl_xor(sv, 32);
    if (lane < 32) {
        agg[(size_t)node * 32 + lane] = aggv;
        if (c == 0) ssum[(size_t)node * 8 + h] = sv;
    }
}

// ---- h[n] = ELU((agg/s) @ W1_head + b1), fp16 out + fused layer-2 dots.
__global__ __launch_bounds__(256) void h_kernel(
    const float* __restrict__ agg, const float* __restrict__ ssum,
    const float4* __restrict__ w1t, const float* __restrict__ b1,
    const float2* __restrict__ wa2t,
    __half* __restrict__ h2buf, float* __restrict__ a2s, float* __restrict__ a2d, int N)
{
    int gid = blockIdx.x * blockDim.x + threadIdx.x;
    int node = gid >> 6;
    if (node >= N) return;
    int lane = threadIdx.x & 63;
    bool act = lane < 60;

    float psrc = 0.f, pdst = 0.f;
    #pragma unroll
    for (int h = 0; h < 8; ++h) {
        float4 ag  = *(const float4*)(agg + (size_t)node * 32 + h * 4);  // uniform
        float  inv = 1.f / (ssum[(size_t)node * 8 + h] + 1e-16f);        // uniform
        if (act) {
            int col = h * 60 + lane;
            float4 w  = w1t[col];
            float raw = ag.x * w.x + ag.y * w.y + ag.z * w.z + ag.w * w.w;
            float v   = raw * inv + b1[col];
            float o   = v > 0.f ? v : expm1f(v);
            h2buf[(size_t)node * 480 + col] = __float2half(o);
            float2 wz = wa2t[col];
            psrc += o * wz.x;
            pdst += o * wz.y;
        }
    }
    #pragma unroll
    for (int off = 32; off; off >>= 1) {
        psrc += __shfl_xor(psrc, off);
        pdst += __shfl_xor(pdst, off);
    }
    if (lane == 0) { a2s[node] = psrc; a2d[node] = pdst; }
}

// ---- xh2h[N,96] = h2[N,480] @ W2[480,96] via MFMA fp16 (f32 accum).
// Block = 256 thr = 4 waves; wave w owns rows m0 = blk*64 + w*16, all 96 cols.
// A-frag: A[lane&15][k0 + (lane>>4)*8 + i]; B-frag from W2t[n][k] same
// pattern; C/D: col = lane&15, row = (lane>>4)*4 + j.
__global__ __launch_bounds__(256) void gemm2_mfma(
    const __half* __restrict__ h2, const __half* __restrict__ w2t,
    __half* __restrict__ xh2h, int N)
{
    int wave = threadIdx.x >> 6;
    int lane = threadIdx.x & 63;
    int m0 = blockIdx.x * 64 + wave * 16;
    int ra   = lane & 15;
    int kgrp = lane >> 4;
    int m = m0 + ra;  if (m > N - 1) m = N - 1;   // clamp: OOB rows duplicate N-1

    floatx4 acc[6];
    #pragma unroll
    for (int n = 0; n < 6; ++n) acc[n] = (floatx4){0.f, 0.f, 0.f, 0.f};

    const _Float16* arow = (const _Float16*)(h2 + (size_t)m * 480);
    const _Float16* wt   = (const _Float16*)w2t;
    for (int k0 = 0; k0 < 480; k0 += 32) {
        half8 af = *(const half8*)(arow + k0 + kgrp * 8);
        #pragma unroll
        for (int n = 0; n < 6; ++n) {
            half8 bf = *(const half8*)(wt + (size_t)(n * 16 + ra) * 480 + k0 + kgrp * 8);
            acc[n] = __builtin_amdgcn_mfma_f32_16x16x32_f16(af, bf, acc[n], 0, 0, 0);
        }
    }
    #pragma unroll
    for (int n = 0; n < 6; ++n) {
        int c = n * 16 + ra;
        #pragma unroll
        for (int j = 0; j < 4; ++j) {
            int r = m0 + kgrp * 4 + j;
            if (r < N) xh2h[(size_t)r * 96 + c] = __float2half(acc[n][j]);
        }
    }
}

// ---- GAT layer 2, fused (unchanged): wave/node, U=8; lane<48 owns {2l,2l+1}
__global__ __launch_bounds__(256) void gat2_fused(
    const int* __restrict__ row_ptr, const int* __restrict__ csr,
    const float* __restrict__ a_s2, const float* __restrict__ a_d2,
    const __half* __restrict__ xh2h, const float* __restrict__ b2,
    float* __restrict__ out, int N)
{
    int gid = blockIdx.x * blockDim.x + threadIdx.x;
    int node = gid >> 6;
    if (node >= N) return;
    int lane = threadIdx.x & 63;
    bool act = lane < 48;
    float adv = a_d2[node];
    float s = 0.f, ax = 0.f, ay = 0.f;
    int beg = row_ptr[node], end = row_ptr[node + 1];
    constexpr int U = 8;
    for (int e0 = beg; e0 < end; e0 += U) {
        int cnt = end - e0;  if (cnt > U) cnt = U;
        int srcs[U];
        #pragma unroll
        for (int u = 0; u < U; ++u) {
            int t = e0 + u;
            srcs[u] = csr[t < end ? t : (end - 1)];
        }
        float asv[U];
        #pragma unroll
        for (int u = 0; u < U; ++u) asv[u] = a_s2[srcs[u]];
        __half2 gv[U];
        if (act) {
            #pragma unroll
            for (int u = 0; u < U; ++u)
                gv[u] = ((const __half2*)(xh2h + (size_t)srcs[u] * 96))[lane];
        }
        #pragma unroll
        for (int u = 0; u < U; ++u) {
            float ev = asv[u] + adv;
            ev = ev > 0.f ? ev : 0.2f * ev;
            float p = __expf(ev) * ((u < cnt) ? 1.f : 0.f);
            s += p;
            if (act) {
                float2 fg = __half22float2(gv[u]);
                ax += p * fg.x;
                ay += p * fg.y;
            }
        }
    }
    float inv = 1.f / (s + 1e-16f);
    if (act) {
        out[(size_t)node * 96 + 2 * lane]     = ax * inv + b2[2 * lane];
        out[(size_t)node * 96 + 2 * lane + 1] = ay * inv + b2[2 * lane + 1];
    }
}

extern "C" void kernel_launch(void* const* d_in, const int* in_sizes, int n_in,
                              void* d_out, int out_size, void* d_ws, size_t ws_size,
                              hipStream_t stream)
{
    const float* x   = (const float*)d_in[0];
    const int*   ei  = (const int*)  d_in[1];
    const float* W1  = (const float*)d_in[2];
    const float* as1 = (const float*)d_in[3];
    const float* ad1 = (const float*)d_in[4];
    const float* b1  = (const float*)d_in[5];
    const float* W2  = (const float*)d_in[6];
    const float* as2 = (const float*)d_in[7];
    const float* ad2 = (const float*)d_in[8];
    const float* b2  = (const float*)d_in[9];
    float* out = (float*)d_out;

    int N  = in_sizes[0] / 4;   // 50000
    int E  = in_sizes[1] / 2;   // 800000
    int EP = E + N;
    int NB = (N + 1023) / 1024; // <= 64 scan blocks (49 here)

    float* f = (float*)d_ws;
    float* a_s1  = f;  f += (size_t)N * 8;
    float* a_d1  = f;  f += (size_t)N * 8;
    float* agg   = f;  f += (size_t)N * 32;
    float* ssum  = f;  f += (size_t)N * 8;
    float* a_s2  = f;  f += N;
    float* a_d2  = f;  f += N;
    float* wa1   = f;  f += 64;
    float4* w1t  = (float4*)f;  f += 480 * 4;
    float2* wa2t = (float2*)f;  f += 480 * 2;
    __half* h2buf = (__half*)f;                 // f32 count so far: N*58+2944 (div 4 -> 16B aligned)
    __half* hp   = h2buf + (size_t)N * 480;
    __half* xh2h = hp;   hp += (size_t)N * 96;
    __half* w2t  = hp;   hp += 96 * 480;
    int* ip      = (int*)hp;
    int* row_ptr = ip;  ip += N + 1;
    int* deg     = ip;  ip += N;
    int* cursor  = ip;  ip += N;
    int* partials= ip;  ip += 64;
    int* csr     = ip;  ip += EP;

    size_t needed = (size_t)((char*)ip - (char*)d_ws);
    if (needed > ws_size) return;  // loud failure if scratch too small

    hipMemsetAsync(deg, 0, (size_t)N * sizeof(int), stream);
    prep_kernel<<<1, 512, 0, stream>>>(W1, as1, ad1, W2, as2, ad2, wa1, w1t, wa2t);
    w2t_kernel<<<(96 * 480 + 255) / 256, 256, 0, stream>>>(W2, w2t);
    a1_kernel<<<(N + 255) / 256, 256, 0, stream>>>(x, wa1, a_s1, a_d1, N);
    degree_kernel<<<(EP + 255) / 256, 256, 0, stream>>>(ei, E, N, deg);
    scan_blk_kernel<<<NB, 1024, 0, stream>>>(deg, N, row_ptr, partials);
    scan_part_kernel<<<1, 64, 0, stream>>>(partials, NB, row_ptr, N);
    scan_add_kernel<<<NB, 1024, 0, stream>>>(row_ptr, partials, cursor, N);
    scatter_kernel<<<(EP + 255) / 256, 256, 0, stream>>>(ei, E, N, cursor, csr);
    gat1_agg<<<(N * 64 + 255) / 256, 256, 0, stream>>>(
        row_ptr, csr, x, a_s1, a_d1, agg, ssum, N);
    h_kernel<<<(N * 64 + 255) / 256, 256, 0, stream>>>(
        agg, ssum, w1t, b1, wa2t, h2buf, a_s2, a_d2, N);
    gemm2_mfma<<<(N + 63) / 64, 256, 0, stream>>>(h2buf, w2t, xh2h, N);
    gat2_fused<<<(N * 64 + 255) / 256, 256, 0, stream>>>(
        row_ptr, csr, a_s2, a_d2, xh2h, b2, out, N);
}

// Round 12
// 243.778 us; speedup vs baseline: 2.2325x; 1.0952x over previous
//
#include <hip/hip_runtime.h>
#include <hip/hip_bf16.h>
#include <hip/hip_fp16.h>
#include <cstdint>
#include <cstddef>

// ---------------------------------------------------------------------------
// FeatureExtractorGAT, round 12.
// Changes vs R11 (267 us; scatter 60 us latency/line-bound, h_kernel 58 us
// VALU-bound on expm1f + per-node table reloads):
//  - h_kernel: ELU via __expf(v)-1 (v_exp_f32; was libm expm1f ~20 instrs),
//    w1t/wa2t/b1 staged in LDS once per 4-node block (4x less L1 traffic).
//  - scatter/degree: 4 edges/thread with int4 edge loads -> 4 atomics in
//    flight per thread (MLP). csr line ping-pong remains (WRITE_SIZE ~55MB
//    is the diagnostic; if unchanged, that cost is structural).
// Everything else unchanged from R11 (MFMA gemm2, input-space gat1, fused
// gat2, parallel scan).
// ---------------------------------------------------------------------------

typedef _Float16 half8 __attribute__((ext_vector_type(8)));
typedef float floatx4 __attribute__((ext_vector_type(4)));

__global__ void prep_kernel(const float* __restrict__ W1,
                            const float* __restrict__ as1, const float* __restrict__ ad1,
                            const float* __restrict__ W2,
                            const float* __restrict__ as2, const float* __restrict__ ad2,
                            float* __restrict__ wa1, float4* __restrict__ w1t,
                            float2* __restrict__ wa2t)
{
    int t = threadIdx.x;
    if (t < 480) {
        float accs = 0.f, accd = 0.f;
        #pragma unroll 4
        for (int c = 0; c < 96; ++c) {
            float w = W2[t * 96 + c];
            accs += w * as2[c];
            accd += w * ad2[c];
        }
        wa2t[t] = make_float2(accs, accd);
        w1t[t]  = make_float4(W1[t], W1[480 + t], W1[960 + t], W1[1440 + t]);
    }
    if (t < 32) {
        int k = t >> 3, h = t & 7;
        float accs = 0.f, accd = 0.f;
        for (int c = 0; c < 60; ++c) {
            float w = W1[k * 480 + h * 60 + c];
            accs += w * as1[h * 60 + c];
            accd += w * ad1[h * 60 + c];
        }
        wa1[k * 8 + h]      = accs;
        wa1[32 + k * 8 + h] = accd;
    }
}

// W2t[n][k] = W2[k][n], fp16
__global__ void w2t_kernel(const float* __restrict__ W2, __half* __restrict__ w2t)
{
    int idx = blockIdx.x * 256 + threadIdx.x;
    if (idx >= 96 * 480) return;
    int n = idx / 480, k = idx - n * 480;
    w2t[idx] = __float2half(W2[k * 96 + n]);
}

__global__ void a1_kernel(const float* __restrict__ x, const float* __restrict__ wa1,
                          float* __restrict__ a_s1, float* __restrict__ a_d1, int N)
{
    int n = blockIdx.x * blockDim.x + threadIdx.x;
    if (n >= N) return;
    float4 xv = *(const float4*)(x + (size_t)n * 4);
    #pragma unroll
    for (int h = 0; h < 8; ++h) {
        float as = xv.x * wa1[h] + xv.y * wa1[8 + h] + xv.z * wa1[16 + h] + xv.w * wa1[24 + h];
        float ad = xv.x * wa1[32 + h] + xv.y * wa1[40 + h] + xv.z * wa1[48 + h] + xv.w * wa1[56 + h];
        a_s1[n * 8 + h] = as;
        a_d1[n * 8 + h] = ad;
    }
}

// 4 edges per thread, int4 loads, 4 atomics in flight
__global__ void degree_kernel(const int* __restrict__ ei, int E, int N, int* __restrict__ deg)
{
    int i = (blockIdx.x * blockDim.x + threadIdx.x) * 4;
    if (i + 3 < E) {
        int4 d4 = *(const int4*)(ei + E + i);
        atomicAdd(&deg[d4.x], 1);
        atomicAdd(&deg[d4.y], 1);
        atomicAdd(&deg[d4.z], 1);
        atomicAdd(&deg[d4.w], 1);
    } else {
        #pragma unroll
        for (int u = 0; u < 4; ++u) {
            int e = i + u;
            if (e < E + N) {
                int d = (e < E) ? ei[E + e] : (e - E);
                atomicAdd(&deg[d], 1);
            }
        }
    }
}

__global__ __launch_bounds__(1024) void scan_blk_kernel(const int* __restrict__ deg, int N,
                                                        int* __restrict__ offs,
                                                        int* __restrict__ partials)
{
    __shared__ int wsum[16];
    int i = blockIdx.x * 1024 + threadIdx.x;
    int lane = threadIdx.x & 63, wid = threadIdx.x >> 6;
    int v = (i < N) ? deg[i] : 0;
    int x = v;
    #pragma unroll
    for (int off = 1; off < 64; off <<= 1) {
        int y = __shfl_up(x, off, 64);
        if (lane >= off) x += y;
    }
    if (lane == 63) wsum[wid] = x;
    __syncthreads();
    if (wid == 0) {
        int wv = (lane < 16) ? wsum[lane] : 0;
        #pragma unroll
        for (int off = 1; off < 16; off <<= 1) {
            int y = __shfl_up(wv, off, 64);
            if (lane >= off) wv += y;
        }
        if (lane < 16) wsum[lane] = wv;
    }
    __syncthreads();
    int excl = (wid ? wsum[wid - 1] : 0) + x - v;
    if (i < N) offs[i] = excl;
    if (threadIdx.x == 1023) partials[blockIdx.x] = wsum[15];
}

__global__ void scan_part_kernel(int* __restrict__ partials, int nb,
                                 int* __restrict__ offs, int N)
{
    int lane = threadIdx.x & 63;
    int v = (lane < nb) ? partials[lane] : 0;
    int x = v;
    #pragma unroll
    for (int off = 1; off < 64; off <<= 1) {
        int y = __shfl_up(x, off, 64);
        if (lane >= off) x += y;
    }
    if (lane < nb) partials[lane] = x - v;
    if (lane == 63) offs[N] = x;
}

__global__ __launch_bounds__(1024) void scan_add_kernel(int* __restrict__ offs,
                                                        const int* __restrict__ partials,
                                                        int* __restrict__ cursor, int N)
{
    int i = blockIdx.x * 1024 + threadIdx.x;
    if (i < N) {
        int r = offs[i] + partials[blockIdx.x];
        offs[i]   = r;
        cursor[i] = r;
    }
}

// 4 edges per thread, int4 loads
__global__ void scatter_kernel(const int* __restrict__ ei, int E, int N,
                               int* __restrict__ cursor, int* __restrict__ csr)
{
    int i = (blockIdx.x * blockDim.x + threadIdx.x) * 4;
    if (i + 3 < E) {
        int4 s4 = *(const int4*)(ei + i);
        int4 d4 = *(const int4*)(ei + E + i);
        int p0 = atomicAdd(&cursor[d4.x], 1);
        int p1 = atomicAdd(&cursor[d4.y], 1);
        int p2 = atomicAdd(&cursor[d4.z], 1);
        int p3 = atomicAdd(&cursor[d4.w], 1);
        csr[p0] = s4.x;
        csr[p1] = s4.y;
        csr[p2] = s4.z;
        csr[p3] = s4.w;
    } else {
        #pragma unroll
        for (int u = 0; u < 4; ++u) {
            int e = i + u;
            if (e < E + N) {
                int s, d;
                if (e < E) { s = ei[e]; d = ei[E + e]; } else { s = d = e - E; }
                int pos = atomicAdd(&cursor[d], 1);
                csr[pos] = s;
            }
        }
    }
}

// ---- GAT layer 1 aggregation in INPUT space (unchanged).
__global__ __launch_bounds__(256) void gat1_agg(
    const int* __restrict__ row_ptr, const int* __restrict__ csr,
    const float* __restrict__ x,
    const float* __restrict__ a_s1, const float* __restrict__ a_d1,
    float* __restrict__ agg, float* __restrict__ ssum, int N)
{
    int gid = blockIdx.x * blockDim.x + threadIdx.x;
    int node = gid >> 6;
    if (node >= N) return;
    int lane = threadIdx.x & 63;
    int half = lane >> 5;
    int sl   = lane & 31;
    int h = sl >> 2, c = sl & 3;
    float adh = a_d1[(size_t)node * 8 + h];

    float aggv = 0.f, sv = 0.f;
    int beg = row_ptr[node], end = row_ptr[node + 1];
    constexpr int U = 4;
    for (int base = beg; base < end; base += 2 * U) {
        int   idx[U];
        float msk[U];
        #pragma unroll
        for (int u = 0; u < U; ++u) {
            int t = base + 2 * u + half;
            msk[u] = (t < end) ? 1.f : 0.f;
            idx[u] = csr[t < end ? t : (end - 1)];
        }
        float xv[U], av[U];
        #pragma unroll
        for (int u = 0; u < U; ++u) xv[u] = x[(size_t)idx[u] * 4 + c];
        #pragma unroll
        for (int u = 0; u < U; ++u) av[u] = a_s1[(size_t)idx[u] * 8 + h];
        #pragma unroll
        for (int u = 0; u < U; ++u) {
            float ev = av[u] + adh;
            ev = ev > 0.f ? ev : 0.2f * ev;
            float p = __expf(ev) * msk[u];
            sv   += p;
            aggv += p * xv[u];
        }
    }
    aggv += __shfl_xor(aggv, 32);
    sv   += __shfl_xor(sv, 32);
    if (lane < 32) {
        agg[(size_t)node * 32 + lane] = aggv;
        if (c == 0) ssum[(size_t)node * 8 + h] = sv;
    }
}

// ---- h[n] = ELU((agg/s) @ W1_head + b1), fp16 out + fused layer-2 dots.
// Tables staged in LDS once per block (4 nodes/block); ELU via __expf-1.
__global__ __launch_bounds__(256) void h_kernel(
    const float* __restrict__ agg, const float* __restrict__ ssum,
    const float4* __restrict__ w1t, const float* __restrict__ b1,
    const float2* __restrict__ wa2t,
    __half* __restrict__ h2buf, float* __restrict__ a2s, float* __restrict__ a2d, int N)
{
    __shared__ float4 w1s[480];
    __shared__ float2 wa2s[480];
    __shared__ float  b1s[480];
    int t = threadIdx.x;
    for (int i = t; i < 480; i += 256) {
        w1s[i]  = w1t[i];
        wa2s[i] = wa2t[i];
        b1s[i]  = b1[i];
    }
    __syncthreads();

    int node = blockIdx.x * 4 + (t >> 6);
    if (node >= N) return;
    int lane = t & 63;
    bool act = lane < 60;

    float psrc = 0.f, pdst = 0.f;
    #pragma unroll
    for (int h = 0; h < 8; ++h) {
        float4 ag  = *(const float4*)(agg + (size_t)node * 32 + h * 4);  // uniform
        float  inv = 1.f / (ssum[(size_t)node * 8 + h] + 1e-16f);        // uniform
        if (act) {
            int col = h * 60 + lane;
            float4 w  = w1s[col];
            float raw = ag.x * w.x + ag.y * w.y + ag.z * w.z + ag.w * w.w;
            float v   = raw * inv + b1s[col];
            float o   = v > 0.f ? v : (__expf(v) - 1.f);
            h2buf[(size_t)node * 480 + col] = __float2half(o);
            float2 wz = wa2s[col];
            psrc += o * wz.x;
            pdst += o * wz.y;
        }
    }
    #pragma unroll
    for (int off = 32; off; off >>= 1) {
        psrc += __shfl_xor(psrc, off);
        pdst += __shfl_xor(pdst, off);
    }
    if (lane == 0) { a2s[node] = psrc; a2d[node] = pdst; }
}

// ---- xh2h[N,96] = h2[N,480] @ W2[480,96] via MFMA fp16 (f32 accum).
__global__ __launch_bounds__(256) void gemm2_mfma(
    const __half* __restrict__ h2, const __half* __restrict__ w2t,
    __half* __restrict__ xh2h, int N)
{
    int wave = threadIdx.x >> 6;
    int lane = threadIdx.x & 63;
    int m0 = blockIdx.x * 64 + wave * 16;
    int ra   = lane & 15;
    int kgrp = lane >> 4;
    int m = m0 + ra;  if (m > N - 1) m = N - 1;   // clamp: OOB rows duplicate N-1

    floatx4 acc[6];
    #pragma unroll
    for (int n = 0; n < 6; ++n) acc[n] = (floatx4){0.f, 0.f, 0.f, 0.f};

    const _Float16* arow = (const _Float16*)(h2 + (size_t)m * 480);
    const _Float16* wt   = (const _Float16*)w2t;
    for (int k0 = 0; k0 < 480; k0 += 32) {
        half8 af = *(const half8*)(arow + k0 + kgrp * 8);
        #pragma unroll
        for (int n = 0; n < 6; ++n) {
            half8 bf = *(const half8*)(wt + (size_t)(n * 16 + ra) * 480 + k0 + kgrp * 8);
            acc[n] = __builtin_amdgcn_mfma_f32_16x16x32_f16(af, bf, acc[n], 0, 0, 0);
        }
    }
    #pragma unroll
    for (int n = 0; n < 6; ++n) {
        int c = n * 16 + ra;
        #pragma unroll
        for (int j = 0; j < 4; ++j) {
            int r = m0 + kgrp * 4 + j;
            if (r < N) xh2h[(size_t)r * 96 + c] = __float2half(acc[n][j]);
        }
    }
}

// ---- GAT layer 2, fused (unchanged): wave/node, U=8; lane<48 owns {2l,2l+1}
__global__ __launch_bounds__(256) void gat2_fused(
    const int* __restrict__ row_ptr, const int* __restrict__ csr,
    const float* __restrict__ a_s2, const float* __restrict__ a_d2,
    const __half* __restrict__ xh2h, const float* __restrict__ b2,
    float* __restrict__ out, int N)
{
    int gid = blockIdx.x * blockDim.x + threadIdx.x;
    int node = gid >> 6;
    if (node >= N) return;
    int lane = threadIdx.x & 63;
    bool act = lane < 48;
    float adv = a_d2[node];
    float s = 0.f, ax = 0.f, ay = 0.f;
    int beg = row_ptr[node], end = row_ptr[node + 1];
    constexpr int U = 8;
    for (int e0 = beg; e0 < end; e0 += U) {
        int cnt = end - e0;  if (cnt > U) cnt = U;
        int srcs[U];
        #pragma unroll
        for (int u = 0; u < U; ++u) {
            int t = e0 + u;
            srcs[u] = csr[t < end ? t : (end - 1)];
        }
        float asv[U];
        #pragma unroll
        for (int u = 0; u < U; ++u) asv[u] = a_s2[srcs[u]];
        __half2 gv[U];
        if (act) {
            #pragma unroll
            for (int u = 0; u < U; ++u)
                gv[u] = ((const __half2*)(xh2h + (size_t)srcs[u] * 96))[lane];
        }
        #pragma unroll
        for (int u = 0; u < U; ++u) {
            float ev = asv[u] + adv;
            ev = ev > 0.f ? ev : 0.2f * ev;
            float p = __expf(ev) * ((u < cnt) ? 1.f : 0.f);
            s += p;
            if (act) {
                float2 fg = __half22float2(gv[u]);
                ax += p * fg.x;
                ay += p * fg.y;
            }
        }
    }
    float inv = 1.f / (s + 1e-16f);
    if (act) {
        out[(size_t)node * 96 + 2 * lane]     = ax * inv + b2[2 * lane];
        out[(size_t)node * 96 + 2 * lane + 1] = ay * inv + b2[2 * lane + 1];
    }
}

extern "C" void kernel_launch(void* const* d_in, const int* in_sizes, int n_in,
                              void* d_out, int out_size, void* d_ws, size_t ws_size,
                              hipStream_t stream)
{
    const float* x   = (const float*)d_in[0];
    const int*   ei  = (const int*)  d_in[1];
    const float* W1  = (const float*)d_in[2];
    const float* as1 = (const float*)d_in[3];
    const float* ad1 = (const float*)d_in[4];
    const float* b1  = (const float*)d_in[5];
    const float* W2  = (const float*)d_in[6];
    const float* as2 = (const float*)d_in[7];
    const float* ad2 = (const float*)d_in[8];
    const float* b2  = (const float*)d_in[9];
    float* out = (float*)d_out;

    int N  = in_sizes[0] / 4;   // 50000
    int E  = in_sizes[1] / 2;   // 800000
    int EP = E + N;
    int NB = (N + 1023) / 1024; // <= 64 scan blocks (49 here)

    float* f = (float*)d_ws;
    float* a_s1  = f;  f += (size_t)N * 8;
    float* a_d1  = f;  f += (size_t)N * 8;
    float* agg   = f;  f += (size_t)N * 32;
    float* ssum  = f;  f += (size_t)N * 8;
    float* a_s2  = f;  f += N;
    float* a_d2  = f;  f += N;
    float* wa1   = f;  f += 64;
    float4* w1t  = (float4*)f;  f += 480 * 4;
    float2* wa2t = (float2*)f;  f += 480 * 2;
    __half* h2buf = (__half*)f;
    __half* hp   = h2buf + (size_t)N * 480;
    __half* xh2h = hp;   hp += (size_t)N * 96;
    __half* w2t  = hp;   hp += 96 * 480;
    int* ip      = (int*)hp;
    int* row_ptr = ip;  ip += N + 1;
    int* deg     = ip;  ip += N;
    int* cursor  = ip;  ip += N;
    int* partials= ip;  ip += 64;
    int* csr     = ip;  ip += EP;

    size_t needed = (size_t)((char*)ip - (char*)d_ws);
    if (needed > ws_size) return;  // loud failure if scratch too small

    hipMemsetAsync(deg, 0, (size_t)N * sizeof(int), stream);
    prep_kernel<<<1, 512, 0, stream>>>(W1, as1, ad1, W2, as2, ad2, wa1, w1t, wa2t);
    w2t_kernel<<<(96 * 480 + 255) / 256, 256, 0, stream>>>(W2, w2t);
    a1_kernel<<<(N + 255) / 256, 256, 0, stream>>>(x, wa1, a_s1, a_d1, N);
    degree_kernel<<<(EP + 1023) / 1024, 256, 0, stream>>>(ei, E, N, deg);
    scan_blk_kernel<<<NB, 1024, 0, stream>>>(deg, N, row_ptr, partials);
    scan_part_kernel<<<1, 64, 0, stream>>>(partials, NB, row_ptr, N);
    scan_add_kernel<<<NB, 1024, 0, stream>>>(row_ptr, partials, cursor, N);
    scatter_kernel<<<(EP + 1023) / 1024, 256, 0, stream>>>(ei, E, N, cursor, csr);
    gat1_agg<<<(N * 64 + 255) / 256, 256, 0, stream>>>(
        row_ptr, csr, x, a_s1, a_d1, agg, ssum, N);
    h_kernel<<<(N + 3) / 4, 256, 0, stream>>>(
        agg, ssum, w1t, b1, wa2t, h2buf, a_s2, a_d2, N);
    gemm2_mfma<<<(N + 63) / 64, 256, 0, stream>>>(h2buf, w2t, xh2h, N);
    gat2_fused<<<(N * 64 + 255) / 256, 256, 0, stream>>>(
        row_ptr, csr, a_s2, a_d2, xh2h, b2, out, N);
}

// Round 13
// 197.092 us; speedup vs baseline: 2.7614x; 1.2369x over previous
//
#include <hip/hip_runtime.h>
#include <hip/hip_bf16.h>
#include <hip/hip_fp16.h>
#include <cstdint>
#include <cstddef>

// ---------------------------------------------------------------------------
// FeatureExtractorGAT, round 13.
// Change vs R12 (244 us; scatter_kernel 53 us, VALU 0.25%, WRITE_SIZE 55.7MB
// -> structural cross-XCD line ping-pong on random 4B csr writes):
//   CSR build rewritten as dst-bucketed multisplit:
//     bucket_hist  : LDS-aggregated per-128-node-bucket histogram
//     bucket_scan  : 391-entry scan (1 block); row_ptr[N]=EP
//     multisplit   : blocks reserve per-bucket chunks (1 global atomic per
//                    nonempty bucket per block), write (src,dst) int2 into
//                    own chunks -> same-XCD write locality
//     csrfill2     : 1 block per bucket; dst histogram + scan + cursors all
//                    in LDS; row_ptr slice + csr written to block-exclusive
//                    window. degree/scan_blk/scan_part/scan_add/scatter and
//                    ALL global cursor atomics: deleted.
// Everything else unchanged from R12.
// ---------------------------------------------------------------------------

typedef _Float16 half8 __attribute__((ext_vector_type(8)));
typedef float floatx4 __attribute__((ext_vector_type(4)));

constexpr int BSH = 7;            // 128 nodes per bucket
constexpr int MAXBUK = 512;       // supports N <= 65536

__global__ void prep_kernel(const float* __restrict__ W1,
                            const float* __restrict__ as1, const float* __restrict__ ad1,
                            const float* __restrict__ W2,
                            const float* __restrict__ as2, const float* __restrict__ ad2,
                            float* __restrict__ wa1, float4* __restrict__ w1t,
                            float2* __restrict__ wa2t)
{
    int t = threadIdx.x;
    if (t < 480) {
        float accs = 0.f, accd = 0.f;
        #pragma unroll 4
        for (int c = 0; c < 96; ++c) {
            float w = W2[t * 96 + c];
            accs += w * as2[c];
            accd += w * ad2[c];
        }
        wa2t[t] = make_float2(accs, accd);
        w1t[t]  = make_float4(W1[t], W1[480 + t], W1[960 + t], W1[1440 + t]);
    }
    if (t < 32) {
        int k = t >> 3, h = t & 7;
        float accs = 0.f, accd = 0.f;
        for (int c = 0; c < 60; ++c) {
            float w = W1[k * 480 + h * 60 + c];
            accs += w * as1[h * 60 + c];
            accd += w * ad1[h * 60 + c];
        }
        wa1[k * 8 + h]      = accs;
        wa1[32 + k * 8 + h] = accd;
    }
}

// W2t[n][k] = W2[k][n], fp16
__global__ void w2t_kernel(const float* __restrict__ W2, __half* __restrict__ w2t)
{
    int idx = blockIdx.x * 256 + threadIdx.x;
    if (idx >= 96 * 480) return;
    int n = idx / 480, k = idx - n * 480;
    w2t[idx] = __float2half(W2[k * 96 + n]);
}

__global__ void a1_kernel(const float* __restrict__ x, const float* __restrict__ wa1,
                          float* __restrict__ a_s1, float* __restrict__ a_d1, int N)
{
    int n = blockIdx.x * blockDim.x + threadIdx.x;
    if (n >= N) return;
    float4 xv = *(const float4*)(x + (size_t)n * 4);
    #pragma unroll
    for (int h = 0; h < 8; ++h) {
        float as = xv.x * wa1[h] + xv.y * wa1[8 + h] + xv.z * wa1[16 + h] + xv.w * wa1[24 + h];
        float ad = xv.x * wa1[32 + h] + xv.y * wa1[40 + h] + xv.z * wa1[48 + h] + xv.w * wa1[56 + h];
        a_s1[n * 8 + h] = as;
        a_d1[n * 8 + h] = ad;
    }
}

// ---- CSR build pass 1: per-bucket histogram (LDS-aggregated)
__global__ __launch_bounds__(256) void bucket_hist(const int* __restrict__ ei, int E, int N,
                                                   int* __restrict__ bcnt)
{
    __shared__ int lcnt[MAXBUK];
    int t = threadIdx.x;
    int nbuk = (N + 127) >> BSH;
    for (int b = t; b < nbuk; b += 256) lcnt[b] = 0;
    __syncthreads();
    #pragma unroll
    for (int u = 0; u < 8; ++u) {
        int e = blockIdx.x * 2048 + u * 256 + t;
        if (e < E + N) {
            int d = (e < E) ? ei[E + e] : (e - E);
            atomicAdd(&lcnt[d >> BSH], 1);
        }
    }
    __syncthreads();
    for (int b = t; b < nbuk; b += 256)
        if (lcnt[b]) atomicAdd(&bcnt[b], lcnt[b]);
}

// ---- CSR build pass 2: scan bucket counts (1 block, 512 thr)
__global__ __launch_bounds__(512) void bucket_scan(const int* __restrict__ bcnt, int nbuk,
                                                   int* __restrict__ boff,
                                                   int* __restrict__ bcursor,
                                                   int* __restrict__ row_ptr, int N)
{
    __shared__ int wsum[8];
    int t = threadIdx.x, lane = t & 63, wid = t >> 6;
    int v = (t < nbuk) ? bcnt[t] : 0;
    int x = v;
    #pragma unroll
    for (int off = 1; off < 64; off <<= 1) {
        int y = __shfl_up(x, off, 64);
        if (lane >= off) x += y;
    }
    if (lane == 63) wsum[wid] = x;
    __syncthreads();
    if (wid == 0) {
        int wv = (lane < 8) ? wsum[lane] : 0;
        #pragma unroll
        for (int off = 1; off < 8; off <<= 1) {
            int y = __shfl_up(wv, off, 64);
            if (lane >= off) wv += y;
        }
        if (lane < 8) wsum[lane] = wv;
    }
    __syncthreads();
    int excl = (wid ? wsum[wid - 1] : 0) + x - v;
    if (t < nbuk) { boff[t] = excl; bcursor[t] = excl; }
    if (t == nbuk - 1) { boff[nbuk] = excl + v; row_ptr[N] = excl + v; }
}

// ---- CSR build pass 3: multisplit (src,dst) pairs into bucket regions.
// Per block: LDS rank per edge, ONE global atomic per nonempty bucket.
__global__ __launch_bounds__(256) void multisplit(const int* __restrict__ ei, int E, int N,
                                                  int* __restrict__ bcursor,
                                                  int2* __restrict__ ebuf)
{
    __shared__ int lcnt[MAXBUK];
    __shared__ int lbase[MAXBUK];
    int t = threadIdx.x;
    int nbuk = (N + 127) >> BSH;
    for (int b = t; b < nbuk; b += 256) lcnt[b] = 0;
    __syncthreads();
    constexpr int U = 16;
    int ss[U], dd[U], rk[U];
    bool ok[U];
    #pragma unroll
    for (int u = 0; u < U; ++u) {
        int e = blockIdx.x * (256 * U) + u * 256 + t;
        ok[u] = e < E + N;
        if (ok[u]) {
            if (e < E) { ss[u] = ei[e]; dd[u] = ei[E + e]; } else { ss[u] = dd[u] = e - E; }
            rk[u] = atomicAdd(&lcnt[dd[u] >> BSH], 1);
        }
    }
    __syncthreads();
    for (int b = t; b < nbuk; b += 256)
        lbase[b] = lcnt[b] ? atomicAdd(&bcursor[b], lcnt[b]) : 0;
    __syncthreads();
    #pragma unroll
    for (int u = 0; u < U; ++u)
        if (ok[u]) ebuf[(size_t)lbase[dd[u] >> BSH] + rk[u]] = make_int2(ss[u], dd[u]);
}

// ---- CSR build pass 4: one block per bucket; all cursors in LDS;
// row_ptr slice + csr written to a block-exclusive window.
__global__ __launch_bounds__(256) void csrfill2(const int2* __restrict__ ebuf,
                                                const int* __restrict__ boff,
                                                int* __restrict__ row_ptr,
                                                int* __restrict__ csr, int N)
{
    int b = blockIdx.x;
    int node0 = b << BSH;
    int nnode = N - node0;  if (nnode > 128) nnode = 128;
    int beg = boff[b], end = boff[b + 1];
    __shared__ int hcnt[128], hcur[128];
    __shared__ int wends[4];
    int t = threadIdx.x;
    if (t < 128) hcnt[t] = 0;
    __syncthreads();
    for (int i = beg + t; i < end; i += 256)
        atomicAdd(&hcnt[ebuf[i].y - node0], 1);
    __syncthreads();
    int lane = t & 63, wid = t >> 6;
    int v = (t < 128) ? hcnt[t] : 0;
    int x = v;
    #pragma unroll
    for (int off = 1; off < 64; off <<= 1) {
        int y = __shfl_up(x, off, 64);
        if (lane >= off) x += y;
    }
    if (lane == 63) wends[wid] = x;
    __syncthreads();
    int excl = x - v + ((wid == 1) ? wends[0] : 0);
    if (t < 128) {
        hcur[t] = excl;
        if (t < nnode) row_ptr[node0 + t] = beg + excl;
    }
    __syncthreads();
    for (int i = beg + t; i < end; i += 256) {
        int2 e = ebuf[i];
        int p = atomicAdd(&hcur[e.y - node0], 1);
        csr[(size_t)beg + p] = e.x;
    }
}

// ---- GAT layer 1 aggregation in INPUT space (unchanged).
__global__ __launch_bounds__(256) void gat1_agg(
    const int* __restrict__ row_ptr, const int* __restrict__ csr,
    const float* __restrict__ x,
    const float* __restrict__ a_s1, const float* __restrict__ a_d1,
    float* __restrict__ agg, float* __restrict__ ssum, int N)
{
    int gid = blockIdx.x * blockDim.x + threadIdx.x;
    int node = gid >> 6;
    if (node >= N) return;
    int lane = threadIdx.x & 63;
    int half = lane >> 5;
    int sl   = lane & 31;
    int h = sl >> 2, c = sl & 3;
    float adh = a_d1[(size_t)node * 8 + h];

    float aggv = 0.f, sv = 0.f;
    int beg = row_ptr[node], end = row_ptr[node + 1];
    constexpr int U = 4;
    for (int base = beg; base < end; base += 2 * U) {
        int   idx[U];
        float msk[U];
        #pragma unroll
        for (int u = 0; u < U; ++u) {
            int t = base + 2 * u + half;
            msk[u] = (t < end) ? 1.f : 0.f;
            idx[u] = csr[t < end ? t : (end - 1)];
        }
        float xv[U], av[U];
        #pragma unroll
        for (int u = 0; u < U; ++u) xv[u] = x[(size_t)idx[u] * 4 + c];
        #pragma unroll
        for (int u = 0; u < U; ++u) av[u] = a_s1[(size_t)idx[u] * 8 + h];
        #pragma unroll
        for (int u = 0; u < U; ++u) {
            float ev = av[u] + adh;
            ev = ev > 0.f ? ev : 0.2f * ev;
            float p = __expf(ev) * msk[u];
            sv   += p;
            aggv += p * xv[u];
        }
    }
    aggv += __shfl_xor(aggv, 32);
    sv   += __shfl_xor(sv, 32);
    if (lane < 32) {
        agg[(size_t)node * 32 + lane] = aggv;
        if (c == 0) ssum[(size_t)node * 8 + h] = sv;
    }
}

// ---- h[n] = ELU((agg/s) @ W1_head + b1), fp16 out + fused layer-2 dots.
__global__ __launch_bounds__(256) void h_kernel(
    const float* __restrict__ agg, const float* __restrict__ ssum,
    const float4* __restrict__ w1t, const float* __restrict__ b1,
    const float2* __restrict__ wa2t,
    __half* __restrict__ h2buf, float* __restrict__ a2s, float* __restrict__ a2d, int N)
{
    __shared__ float4 w1s[480];
    __shared__ float2 wa2s[480];
    __shared__ float  b1s[480];
    int t = threadIdx.x;
    for (int i = t; i < 480; i += 256) {
        w1s[i]  = w1t[i];
        wa2s[i] = wa2t[i];
        b1s[i]  = b1[i];
    }
    __syncthreads();

    int node = blockIdx.x * 4 + (t >> 6);
    if (node >= N) return;
    int lane = t & 63;
    bool act = lane < 60;

    float psrc = 0.f, pdst = 0.f;
    #pragma unroll
    for (int h = 0; h < 8; ++h) {
        float4 ag  = *(const float4*)(agg + (size_t)node * 32 + h * 4);  // uniform
        float  inv = 1.f / (ssum[(size_t)node * 8 + h] + 1e-16f);        // uniform
        if (act) {
            int col = h * 60 + lane;
            float4 w  = w1s[col];
            float raw = ag.x * w.x + ag.y * w.y + ag.z * w.z + ag.w * w.w;
            float v   = raw * inv + b1s[col];
            float o   = v > 0.f ? v : (__expf(v) - 1.f);
            h2buf[(size_t)node * 480 + col] = __float2half(o);
            float2 wz = wa2s[col];
            psrc += o * wz.x;
            pdst += o * wz.y;
        }
    }
    #pragma unroll
    for (int off = 32; off; off >>= 1) {
        psrc += __shfl_xor(psrc, off);
        pdst += __shfl_xor(pdst, off);
    }
    if (lane == 0) { a2s[node] = psrc; a2d[node] = pdst; }
}

// ---- xh2h[N,96] = h2[N,480] @ W2[480,96] via MFMA fp16 (f32 accum).
__global__ __launch_bounds__(256) void gemm2_mfma(
    const __half* __restrict__ h2, const __half* __restrict__ w2t,
    __half* __restrict__ xh2h, int N)
{
    int wave = threadIdx.x >> 6;
    int lane = threadIdx.x & 63;
    int m0 = blockIdx.x * 64 + wave * 16;
    int ra   = lane & 15;
    int kgrp = lane >> 4;
    int m = m0 + ra;  if (m > N - 1) m = N - 1;   // clamp: OOB rows duplicate N-1

    floatx4 acc[6];
    #pragma unroll
    for (int n = 0; n < 6; ++n) acc[n] = (floatx4){0.f, 0.f, 0.f, 0.f};

    const _Float16* arow = (const _Float16*)(h2 + (size_t)m * 480);
    const _Float16* wt   = (const _Float16*)w2t;
    for (int k0 = 0; k0 < 480; k0 += 32) {
        half8 af = *(const half8*)(arow + k0 + kgrp * 8);
        #pragma unroll
        for (int n = 0; n < 6; ++n) {
            half8 bf = *(const half8*)(wt + (size_t)(n * 16 + ra) * 480 + k0 + kgrp * 8);
            acc[n] = __builtin_amdgcn_mfma_f32_16x16x32_f16(af, bf, acc[n], 0, 0, 0);
        }
    }
    #pragma unroll
    for (int n = 0; n < 6; ++n) {
        int c = n * 16 + ra;
        #pragma unroll
        for (int j = 0; j < 4; ++j) {
            int r = m0 + kgrp * 4 + j;
            if (r < N) xh2h[(size_t)r * 96 + c] = __float2half(acc[n][j]);
        }
    }
}

// ---- GAT layer 2, fused (unchanged): wave/node, U=8; lane<48 owns {2l,2l+1}
__global__ __launch_bounds__(256) void gat2_fused(
    const int* __restrict__ row_ptr, const int* __restrict__ csr,
    const float* __restrict__ a_s2, const float* __restrict__ a_d2,
    const __half* __restrict__ xh2h, const float* __restrict__ b2,
    float* __restrict__ out, int N)
{
    int gid = blockIdx.x * blockDim.x + threadIdx.x;
    int node = gid >> 6;
    if (node >= N) return;
    int lane = threadIdx.x & 63;
    bool act = lane < 48;
    float adv = a_d2[node];
    float s = 0.f, ax = 0.f, ay = 0.f;
    int beg = row_ptr[node], end = row_ptr[node + 1];
    constexpr int U = 8;
    for (int e0 = beg; e0 < end; e0 += U) {
        int cnt = end - e0;  if (cnt > U) cnt = U;
        int srcs[U];
        #pragma unroll
        for (int u = 0; u < U; ++u) {
            int t = e0 + u;
            srcs[u] = csr[t < end ? t : (end - 1)];
        }
        float asv[U];
        #pragma unroll
        for (int u = 0; u < U; ++u) asv[u] = a_s2[srcs[u]];
        __half2 gv[U];
        if (act) {
            #pragma unroll
            for (int u = 0; u < U; ++u)
                gv[u] = ((const __half2*)(xh2h + (size_t)srcs[u] * 96))[lane];
        }
        #pragma unroll
        for (int u = 0; u < U; ++u) {
            float ev = asv[u] + adv;
            ev = ev > 0.f ? ev : 0.2f * ev;
            float p = __expf(ev) * ((u < cnt) ? 1.f : 0.f);
            s += p;
            if (act) {
                float2 fg = __half22float2(gv[u]);
                ax += p * fg.x;
                ay += p * fg.y;
            }
        }
    }
    float inv = 1.f / (s + 1e-16f);
    if (act) {
        out[(size_t)node * 96 + 2 * lane]     = ax * inv + b2[2 * lane];
        out[(size_t)node * 96 + 2 * lane + 1] = ay * inv + b2[2 * lane + 1];
    }
}

extern "C" void kernel_launch(void* const* d_in, const int* in_sizes, int n_in,
                              void* d_out, int out_size, void* d_ws, size_t ws_size,
                              hipStream_t stream)
{
    const float* x   = (const float*)d_in[0];
    const int*   ei  = (const int*)  d_in[1];
    const float* W1  = (const float*)d_in[2];
    const float* as1 = (const float*)d_in[3];
    const float* ad1 = (const float*)d_in[4];
    const float* b1  = (const float*)d_in[5];
    const float* W2  = (const float*)d_in[6];
    const float* as2 = (const float*)d_in[7];
    const float* ad2 = (const float*)d_in[8];
    const float* b2  = (const float*)d_in[9];
    float* out = (float*)d_out;

    int N  = in_sizes[0] / 4;   // 50000
    int E  = in_sizes[1] / 2;   // 800000
    int EP = E + N;
    int NBUK = (N + 127) >> BSH;            // 391
    int NBK_H = (EP + 2047) / 2048;         // hist blocks
    int NBK_M = (EP + 4095) / 4096;         // multisplit blocks (U=16)

    float* f = (float*)d_ws;
    float* a_s1  = f;  f += (size_t)N * 8;
    float* a_d1  = f;  f += (size_t)N * 8;
    float* agg   = f;  f += (size_t)N * 32;
    float* ssum  = f;  f += (size_t)N * 8;
    float* a_s2  = f;  f += N;
    float* a_d2  = f;  f += N;
    float* wa1   = f;  f += 64;
    float4* w1t  = (float4*)f;  f += 480 * 4;
    float2* wa2t = (float2*)f;  f += 480 * 2;
    __half* h2buf = (__half*)f;
    __half* hp   = h2buf + (size_t)N * 480;
    __half* xh2h = hp;   hp += (size_t)N * 96;
    __half* w2t  = hp;   hp += 96 * 480;
    // int2 region first for 8B alignment (all prior element counts even)
    int2* ebuf   = (int2*)hp;
    int* ip      = (int*)(ebuf + EP);
    int* row_ptr = ip;  ip += N + 1;
    int* bcnt    = ip;  ip += MAXBUK;
    int* boff    = ip;  ip += MAXBUK + 1;
    int* bcursor = ip;  ip += MAXBUK;
    int* csr     = ip;  ip += EP;

    size_t needed = (size_t)((char*)ip - (char*)d_ws);
    if (needed > ws_size) return;  // loud failure if scratch too small

    hipMemsetAsync(bcnt, 0, MAXBUK * sizeof(int), stream);
    prep_kernel<<<1, 512, 0, stream>>>(W1, as1, ad1, W2, as2, ad2, wa1, w1t, wa2t);
    w2t_kernel<<<(96 * 480 + 255) / 256, 256, 0, stream>>>(W2, w2t);
    a1_kernel<<<(N + 255) / 256, 256, 0, stream>>>(x, wa1, a_s1, a_d1, N);
    bucket_hist<<<NBK_H, 256, 0, stream>>>(ei, E, N, bcnt);
    bucket_scan<<<1, 512, 0, stream>>>(bcnt, NBUK, boff, bcursor, row_ptr, N);
    multisplit<<<NBK_M, 256, 0, stream>>>(ei, E, N, bcursor, ebuf);
    csrfill2<<<NBUK, 256, 0, stream>>>(ebuf, boff, row_ptr, csr, N);
    gat1_agg<<<(N * 64 + 255) / 256, 256, 0, stream>>>(
        row_ptr, csr, x, a_s1, a_d1, agg, ssum, N);
    h_kernel<<<(N + 3) / 4, 256, 0, stream>>>(
        agg, ssum, w1t, b1, wa2t, h2buf, a_s2, a_d2, N);
    gemm2_mfma<<<(N + 63) / 64, 256, 0, stream>>>(h2buf, w2t, xh2h, N);
    gat2_fused<<<(N * 64 + 255) / 256, 256, 0, stream>>>(
        row_ptr, csr, a_s2, a_d2, xh2h, b2, out, N);
}